// Round 3
// baseline (604.336 us; speedup 1.0000x reference)
//
#include <hip/hip_runtime.h>
#include <hip/hip_bf16.h>

// VQ nearest-neighbor: N=65536 rows (D=256) vs K=1024 codes.
// Outputs (FLOAT32, concat): emb_out [N*D], ids [N], loss [N].
//   (Reference outputs are f32 -> d_out is float*. Prior rounds wrote bf16;
//    the packed ids landed mid-emb-chunk, producing the exact 1023.9948 error.)
// 3-kernel structure:
//   1) cnorm_k:  ||c_k||^2 -> ws
//   2) argmin_k: tiled f32 GEMM (dist = ||c||^2 - 2 x.c), register-only
//                running argmin, int ids -> ws
//   3) epi_k:    gather (clamped), write emb/ids/loss as f32
// f32 vector-FMA only: no fp32 MFMA on CDNA4; bf16 MFMA would flip argmins.

constexpr int NROWS = 65536;
constexpr int DDIM  = 256;
constexpr int KCB   = 1024;
constexpr int BM    = 128;   // rows per block
constexpr int BN    = 128;   // codes per tile
constexpr int DKC   = 32;    // d-chunk staged in LDS
constexpr float COMMIT_W = 0.25f;
constexpr float BIG = 3.402823466e+38f;

__global__ void cnorm_k(const float* __restrict__ cb, float* __restrict__ cn) {
    int k    = blockIdx.x * 4 + (threadIdx.x >> 6);   // one wave per code
    int lane = threadIdx.x & 63;
    float4 v = *reinterpret_cast<const float4*>(cb + (size_t)k * DDIM + lane * 4);
    float s = v.x * v.x + v.y * v.y + v.z * v.z + v.w * v.w;
    #pragma unroll
    for (int off = 32; off; off >>= 1) s += __shfl_xor(s, off);
    if (lane == 0) cn[k] = s;
}

__launch_bounds__(256, 2)
__global__ void argmin_k(const float* __restrict__ x, const float* __restrict__ cb,
                         const float* __restrict__ cn, int* __restrict__ idsw) {
    __shared__ float Xs[DKC][BM];   // [d][row] so fragment reads are float4
    __shared__ float Cs[DKC][BN];

    const int tid  = threadIdx.x;
    const int n0   = blockIdx.x * BM;
    const int ty   = tid >> 4;       // owns rows ty*8..+7
    const int tx   = tid & 15;       // owns cols tx*8..+7 within tile
    const int srow = tid >> 3;       // staging: 32 rows x 8 col-quads
    const int scol = (tid & 7) << 2;

    float rbv[8]; int rbi[8];        // per-thread running best (registers only)
    #pragma unroll
    for (int i = 0; i < 8; ++i) { rbv[i] = BIG; rbi[i] = 0; }

    for (int ct = 0; ct < KCB; ct += BN) {
        float acc[8][8] = {};
        for (int d0 = 0; d0 < DDIM; d0 += DKC) {
            __syncthreads();   // protect LDS vs previous chunk's readers
            #pragma unroll
            for (int it = 0; it < 4; ++it) {
                int r = srow + it * 32;
                float4 xv = *reinterpret_cast<const float4*>(
                    x + (size_t)(n0 + r) * DDIM + d0 + scol);
                Xs[scol + 0][r] = xv.x; Xs[scol + 1][r] = xv.y;
                Xs[scol + 2][r] = xv.z; Xs[scol + 3][r] = xv.w;
                float4 cv = *reinterpret_cast<const float4*>(
                    cb + (size_t)(ct + r) * DDIM + d0 + scol);
                Cs[scol + 0][r] = cv.x; Cs[scol + 1][r] = cv.y;
                Cs[scol + 2][r] = cv.z; Cs[scol + 3][r] = cv.w;
            }
            __syncthreads();
            #pragma unroll
            for (int d = 0; d < DKC; ++d) {
                float4 xa  = *reinterpret_cast<const float4*>(&Xs[d][ty * 8]);
                float4 xb  = *reinterpret_cast<const float4*>(&Xs[d][ty * 8 + 4]);
                float4 ca  = *reinterpret_cast<const float4*>(&Cs[d][tx * 8]);
                float4 cb4 = *reinterpret_cast<const float4*>(&Cs[d][tx * 8 + 4]);
                float xr[8] = {xa.x, xa.y, xa.z, xa.w, xb.x, xb.y, xb.z, xb.w};
                float cc[8] = {ca.x, ca.y, ca.z, ca.w, cb4.x, cb4.y, cb4.z, cb4.w};
                #pragma unroll
                for (int i = 0; i < 8; ++i)
                    #pragma unroll
                    for (int j = 0; j < 8; ++j)
                        acc[i][j] = fmaf(xr[i], cc[j], acc[i][j]);
            }
        }
        // fused argmin over this 128-code tile, registers + shuffles only
        #pragma unroll
        for (int i = 0; i < 8; ++i) {
            float bv = BIG; int bi = 0;
            #pragma unroll
            for (int j = 0; j < 8; ++j) {
                float v = cn[ct + tx * 8 + j] - 2.0f * acc[i][j];
                int col = ct + tx * 8 + j;
                if (v < bv) { bv = v; bi = col; }   // strict < keeps first min
            }
            #pragma unroll
            for (int off = 1; off < 16; off <<= 1) {  // reduce across 16 tx-lanes
                float v2 = __shfl_xor(bv, off);
                int   i2 = __shfl_xor(bi, off);
                if (v2 < bv || (v2 == bv && i2 < bi)) { bv = v2; bi = i2; }
            }
            if (bv < rbv[i]) { rbv[i] = bv; rbi[i] = bi; }  // earlier ct wins ties
        }
    }
    if (tx == 0) {
        #pragma unroll
        for (int i = 0; i < 8; ++i) idsw[n0 + ty * 8 + i] = rbi[i];
    }
}

__global__ void epi_k(const float* __restrict__ x, const float* __restrict__ cb,
                      const int* __restrict__ idsw, float* __restrict__ out) {
    float* emb = out;                            // [N*D] f32
    float* ido = out + (size_t)NROWS * DDIM;     // [N]   f32 (id value)
    float* lss = ido + NROWS;                    // [N]   f32

    const int row  = blockIdx.x * 4 + (threadIdx.x >> 6);   // one wave per row
    const int lane = threadIdx.x & 63;
    const int bid  = idsw[row];
    const int bc   = bid < 0 ? 0 : (bid > KCB - 1 ? KCB - 1 : bid);  // defensive

    float4 xv = *reinterpret_cast<const float4*>(x  + (size_t)row * DDIM + lane * 4);
    float4 cv = *reinterpret_cast<const float4*>(cb + (size_t)bc  * DDIM + lane * 4);

    *reinterpret_cast<float4*>(emb + (size_t)row * DDIM + lane * 4) = cv;

    float dx = xv.x - cv.x, dy = xv.y - cv.y;
    float dz = xv.z - cv.z, dw = xv.w - cv.w;
    float s = dx * dx + dy * dy + dz * dz + dw * dw;
    #pragma unroll
    for (int off = 32; off; off >>= 1) s += __shfl_xor(s, off);
    if (lane == 0) {
        lss[row] = (1.0f + COMMIT_W) * s;
        ido[row] = (float)bid;
    }
}

extern "C" void kernel_launch(void* const* d_in, const int* in_sizes, int n_in,
                              void* d_out, int out_size, void* d_ws, size_t ws_size,
                              hipStream_t stream) {
    const float* x  = (const float*)d_in[0];
    const float* cb = (const float*)d_in[1];
    if (n_in >= 2 && in_sizes[0] < in_sizes[1]) {   // guard input ordering
        x  = (const float*)d_in[1];
        cb = (const float*)d_in[0];
    }
    float* cn   = (float*)d_ws;                     // [1024] f32
    int*   idsw = (int*)d_ws + KCB;                 // [65536] i32
    float* out  = (float*)d_out;

    cnorm_k <<<KCB / 4,    256, 0, stream>>>(cb, cn);
    argmin_k<<<NROWS / BM, 256, 0, stream>>>(x, cb, cn, idsw);
    epi_k   <<<NROWS / 4,  256, 0, stream>>>(x, cb, idsw, out);
}

// Round 4
// 538.643 us; speedup vs baseline: 1.1220x; 1.1220x over previous
//
#include <hip/hip_runtime.h>

// VQ nearest-neighbor: N=65536 rows (D=256) vs K=1024 codes.
// Outputs (f32, concat): emb_out [N*D], ids [N], loss [N].
// Round 4: (1) XOR quad-swizzled LDS (conflict-free reads AND writes),
//          (2) 8x16 register tile (BN=256) -> FMA/LDS-byte 1.0 -> 1.33,
//          (3) epilogue fused into the GEMM kernel.
// Swizzle: within each LDS row d, physical float4-quad = logical_quad ^ ((d>>2)&7).
//  - reads (d fixed per instr): 8 logical quads XOR const -> 8 distinct quads
//    -> 32 banks, conflict-free; 16B alignment preserved.
//  - writes (lane k-loop, d = scol+k, (d>>2)&7 == tid&7): pq = (r>>2)^(tid&7)
//    -> 8 distinct banks across lanes 0..7, conflict-free.

constexpr int NROWS = 65536;
constexpr int DDIM  = 256;
constexpr int KCB   = 1024;
constexpr int BM    = 128;    // rows per block
constexpr int BN    = 256;    // codes per tile
constexpr int DKC   = 32;     // d-chunk staged in LDS
constexpr int NTILES = KCB / BN;  // 4
constexpr float COMMIT_W = 0.25f;
constexpr float BIG = 3.402823466e+38f;

__global__ void cnorm_k(const float* __restrict__ cb, float* __restrict__ cn) {
    int k    = blockIdx.x * 4 + (threadIdx.x >> 6);   // one wave per code
    int lane = threadIdx.x & 63;
    float4 v = *reinterpret_cast<const float4*>(cb + (size_t)k * DDIM + lane * 4);
    float s = v.x * v.x + v.y * v.y + v.z * v.z + v.w * v.w;
    #pragma unroll
    for (int off = 32; off; off >>= 1) s += __shfl_xor(s, off);
    if (lane == 0) cn[k] = s;
}

__launch_bounds__(256, 2)
__global__ void vq_k(const float* __restrict__ x, const float* __restrict__ cb,
                     const float* __restrict__ cn, float* __restrict__ out) {
    __shared__ __align__(16) float Xs[DKC * BM];   // [d][row], quad-swizzled
    __shared__ __align__(16) float Cs[DKC * BN];   // [d][code], quad-swizzled
    __shared__ int bestiS[BM];

    const int tid  = threadIdx.x;
    const int n0   = blockIdx.x * BM;
    const int ty   = tid >> 4;        // owns rows ty*8..+7
    const int tx   = tid & 15;        // owns cols {q*64 + tx*4 + j}
    const int sg   = tid & 7;         // staging d-quad group == (d>>2)&7
    const int scol = sg << 2;
    const int srow = tid >> 3;        // 0..31

    float rbv[8]; int rbi[8];
    #pragma unroll
    for (int i = 0; i < 8; ++i) { rbv[i] = BIG; rbi[i] = 0; }

    #pragma unroll 1
    for (int ct = 0; ct < NTILES; ++ct) {
        float acc[8][16];
        #pragma unroll
        for (int i = 0; i < 8; ++i)
            #pragma unroll
            for (int j = 0; j < 16; ++j) acc[i][j] = 0.f;

        #pragma unroll 1
        for (int d0 = 0; d0 < DDIM; d0 += DKC) {
            __syncthreads();   // protect LDS vs previous chunk's readers
            #pragma unroll
            for (int it = 0; it < 4; ++it) {           // X: 128 rows x 32 d
                int r  = srow + it * 32;
                int pq = ((((r >> 2) ^ sg) << 2) | (r & 3));
                float4 v = *reinterpret_cast<const float4*>(
                    x + (size_t)(n0 + r) * DDIM + d0 + scol);
                Xs[(scol + 0) * BM + pq] = v.x;
                Xs[(scol + 1) * BM + pq] = v.y;
                Xs[(scol + 2) * BM + pq] = v.z;
                Xs[(scol + 3) * BM + pq] = v.w;
            }
            #pragma unroll
            for (int it = 0; it < 8; ++it) {           // C: 256 codes x 32 d
                int r  = srow + it * 32;
                int pq = ((((r >> 2) ^ sg) << 2) | (r & 3));
                float4 v = *reinterpret_cast<const float4*>(
                    cb + (size_t)(ct * BN + r) * DDIM + d0 + scol);
                Cs[(scol + 0) * BN + pq] = v.x;
                Cs[(scol + 1) * BN + pq] = v.y;
                Cs[(scol + 2) * BN + pq] = v.z;
                Cs[(scol + 3) * BN + pq] = v.w;
            }
            __syncthreads();
            #pragma unroll 1
            for (int dq = 0; dq < 8; ++dq) {           // d-quads
                const int xrow = dq * 4 * BM;
                const int crow = dq * 4 * BN;
                const int xq0  = ((ty * 2    ) ^ dq) << 2;
                const int xq1  = ((ty * 2 + 1) ^ dq) << 2;
                const int cq0  = (((tx +  0) ^ dq) << 2);
                const int cq1  = (((tx + 16) ^ dq) << 2);
                const int cq2  = (((tx + 32) ^ dq) << 2);
                const int cq3  = (((tx + 48) ^ dq) << 2);
                #pragma unroll
                for (int dd = 0; dd < 4; ++dd) {
                    float4 xa = *reinterpret_cast<const float4*>(&Xs[xrow + dd * BM + xq0]);
                    float4 xb = *reinterpret_cast<const float4*>(&Xs[xrow + dd * BM + xq1]);
                    float4 c0 = *reinterpret_cast<const float4*>(&Cs[crow + dd * BN + cq0]);
                    float4 c1 = *reinterpret_cast<const float4*>(&Cs[crow + dd * BN + cq1]);
                    float4 c2 = *reinterpret_cast<const float4*>(&Cs[crow + dd * BN + cq2]);
                    float4 c3 = *reinterpret_cast<const float4*>(&Cs[crow + dd * BN + cq3]);
                    float xr[8]  = {xa.x, xa.y, xa.z, xa.w, xb.x, xb.y, xb.z, xb.w};
                    float cc[16] = {c0.x, c0.y, c0.z, c0.w, c1.x, c1.y, c1.z, c1.w,
                                    c2.x, c2.y, c2.z, c2.w, c3.x, c3.y, c3.z, c3.w};
                    #pragma unroll
                    for (int i = 0; i < 8; ++i)
                        #pragma unroll
                        for (int j = 0; j < 16; ++j)
                            acc[i][j] = fmaf(xr[i], cc[j], acc[i][j]);
                }
            }
        }
        // fused argmin over this 256-code tile (registers + shuffles only)
        float4 cn0 = *reinterpret_cast<const float4*>(&cn[ct * BN +   0 + tx * 4]);
        float4 cn1 = *reinterpret_cast<const float4*>(&cn[ct * BN +  64 + tx * 4]);
        float4 cn2 = *reinterpret_cast<const float4*>(&cn[ct * BN + 128 + tx * 4]);
        float4 cn3 = *reinterpret_cast<const float4*>(&cn[ct * BN + 192 + tx * 4]);
        float cnv[16] = {cn0.x, cn0.y, cn0.z, cn0.w, cn1.x, cn1.y, cn1.z, cn1.w,
                         cn2.x, cn2.y, cn2.z, cn2.w, cn3.x, cn3.y, cn3.z, cn3.w};
        #pragma unroll
        for (int i = 0; i < 8; ++i) {
            float bv = BIG; int bi = 0;
            #pragma unroll
            for (int j = 0; j < 16; ++j) {             // j ascending == col ascending
                float v  = cnv[j] - 2.0f * acc[i][j];
                int col  = ct * BN + (j >> 2) * 64 + tx * 4 + (j & 3);
                if (v < bv) { bv = v; bi = col; }      // strict < keeps first min
            }
            #pragma unroll
            for (int off = 1; off < 16; off <<= 1) {   // reduce across 16 tx-lanes
                float v2 = __shfl_xor(bv, off);
                int   i2 = __shfl_xor(bi, off);
                if (v2 < bv || (v2 == bv && i2 < bi)) { bv = v2; bi = i2; }
            }
            if (bv < rbv[i]) { rbv[i] = bv; rbi[i] = bi; }  // earlier ct wins ties
        }
    }
    if (tx == 0) {
        #pragma unroll
        for (int i = 0; i < 8; ++i) bestiS[ty * 8 + i] = rbi[i];
    }
    __syncthreads();

    // fused epilogue: gather code row -> emb, ids, loss = 1.25*||x-c||^2
    float* emb = out;                            // [N*D]
    float* ido = out + (size_t)NROWS * DDIM;     // [N]
    float* lss = ido + NROWS;                    // [N]
    const int wv = tid >> 6, lane = tid & 63;    // one wave per 32 rows
    for (int r = wv * 32; r < wv * 32 + 32; ++r) {
        int bid = bestiS[r];
        int bc  = bid < 0 ? 0 : (bid > KCB - 1 ? KCB - 1 : bid);
        float4 xv = *reinterpret_cast<const float4*>(x  + (size_t)(n0 + r) * DDIM + lane * 4);
        float4 cv = *reinterpret_cast<const float4*>(cb + (size_t)bc  * DDIM + lane * 4);
        *reinterpret_cast<float4*>(emb + (size_t)(n0 + r) * DDIM + lane * 4) = cv;
        float dx = xv.x - cv.x, dy = xv.y - cv.y;
        float dz = xv.z - cv.z, dw = xv.w - cv.w;
        float s = dx * dx + dy * dy + dz * dz + dw * dw;
        #pragma unroll
        for (int off = 32; off; off >>= 1) s += __shfl_xor(s, off);
        if (lane == 0) {
            lss[n0 + r] = (1.0f + COMMIT_W) * s;
            ido[n0 + r] = (float)bid;
        }
    }
}

extern "C" void kernel_launch(void* const* d_in, const int* in_sizes, int n_in,
                              void* d_out, int out_size, void* d_ws, size_t ws_size,
                              hipStream_t stream) {
    const float* x  = (const float*)d_in[0];
    const float* cb = (const float*)d_in[1];
    if (n_in >= 2 && in_sizes[0] < in_sizes[1]) {   // guard input ordering
        x  = (const float*)d_in[1];
        cb = (const float*)d_in[0];
    }
    float* cn  = (float*)d_ws;                      // [1024] f32
    float* out = (float*)d_out;

    cnorm_k<<<KCB / 4,    256, 0, stream>>>(cb, cn);
    vq_k   <<<NROWS / BM, 256, 0, stream>>>(x, cb, cn, out);
}